// Round 1
// baseline (247.763 us; speedup 1.0000x reference)
//
#include <hip/hip_runtime.h>
#include <stdint.h>
#include <stddef.h>

typedef __bf16 bf16;
typedef __bf16 bf16x8 __attribute__((ext_vector_type(8)));
typedef float f32x4 __attribute__((ext_vector_type(4)));

static_assert(sizeof(bf16x8) == 16, "bf16x8 must be 16B");

__device__ __forceinline__ void gload_lds16(const void* g, void* l) {
    __builtin_amdgcn_global_load_lds(
        (const __attribute__((address_space(1))) uint32_t*)g,
        (__attribute__((address_space(3))) uint32_t*)l, 16, 0, 0);
}

// ---------------------------------------------------------------------------
// Kernel 1: attention  (pool 56x56 -> 28x28, MLP 784->196->16, softmax/T)
// grid = 8 (one block per sample), block = 256
// ---------------------------------------------------------------------------
__global__ void attn_kernel(const float* __restrict__ sk,
                            const float* __restrict__ w1,
                            const float* __restrict__ w2,
                            float* __restrict__ att) {
    const int b = blockIdx.x, t = threadIdx.x;
    __shared__ float pooled[784];
    __shared__ float hdn[196];
    __shared__ float logits[16];
    const float* skb = sk + (size_t)b * 3136;
    for (int e = t; e < 784; e += 256) {
        int oy = e / 28, ox = e % 28;
        const float* p = skb + (oy * 2) * 56 + ox * 2;
        pooled[e] = 0.25f * (p[0] + p[1] + p[56] + p[57]);
    }
    __syncthreads();
    if (t < 196) {
        float s = 0.f;
        const float* wr = w1 + (size_t)t * 784;
        for (int i = 0; i < 784; ++i) s += pooled[i] * wr[i];
        hdn[t] = s > 0.f ? s : 0.f;
    }
    __syncthreads();
    if (t < 16) {
        float s = 0.f;
        const float* wr = w2 + (size_t)t * 196;
        for (int j = 0; j < 196; ++j) s += hdn[j] * wr[j];
        logits[t] = s * (1.0f / 30.0f);
    }
    __syncthreads();
    if (t == 0) {
        float m = logits[0];
        for (int k = 1; k < 16; ++k) m = fmaxf(m, logits[k]);
        float e16[16], sum = 0.f;
        for (int k = 0; k < 16; ++k) { e16[k] = expf(logits[k] - m); sum += e16[k]; }
        float inv = 1.f / sum;
        for (int k = 0; k < 16; ++k) att[b * 16 + k] = e16[k] * inv;
    }
}

// ---------------------------------------------------------------------------
// Kernel 2: weight aggregation + bias aggregation.
// grid = 256 (one block per co), block = 256.
// agg_w2 layout: [b][pos][chunk(4)][half(2)][cg(8)][co_l(128)][c8(8)]  bf16
// ---------------------------------------------------------------------------
__global__ void agg_kernel(const float* __restrict__ weight,
                           const float* __restrict__ bias,
                           const float* __restrict__ att,
                           bf16* __restrict__ aggw,
                           float* __restrict__ aggb) {
    const int co = blockIdx.x, t = threadIdx.x;
    __shared__ float attL[128];
    __shared__ bf16 accW[8 * 2304];  // [b][e = ci*9+pos]
    if (t < 128) attL[t] = att[t];
    __syncthreads();
    if (t < 8) {
        float s = 0.f;
        for (int k = 0; k < 16; ++k) s += attL[t * 16 + k] * bias[k * 256 + co];
        aggb[t * 256 + co] = s;
    }
    const float* wbase = weight + (size_t)co * 2304;
    for (int i = 0; i < 9; ++i) {
        int e = t + 256 * i;
        float a8[8] = {0.f, 0.f, 0.f, 0.f, 0.f, 0.f, 0.f, 0.f};
        for (int k = 0; k < 16; ++k) {
            float v = wbase[(size_t)k * 589824 + e];
#pragma unroll
            for (int bb = 0; bb < 8; ++bb) a8[bb] += attL[bb * 16 + k] * v;
        }
#pragma unroll
        for (int bb = 0; bb < 8; ++bb) accW[bb * 2304 + e] = (bf16)a8[bb];
    }
    __syncthreads();
    // write out in the conv-DMA-native layout
    const int g = t & 31, psub = t >> 5;
    const int half = co >> 7, co_l = co & 127;
    const int chunk = g >> 3, cg = g & 7;
    for (int j = 0; j < 9; ++j) {
        int pair = psub + 8 * j;          // 72 (b,pos) pairs
        int bb = pair / 9, pos = pair % 9;
        bf16x8 v;
#pragma unroll
        for (int c = 0; c < 8; ++c) v[c] = accW[bb * 2304 + (g * 8 + c) * 9 + pos];
        size_t o = (((((size_t)bb * 9 + pos) * 4 + chunk) * 2 + half) * 8 + cg) * 128 + co_l;
        *(bf16x8*)(aggw + o * 8) = v;
    }
}

// ---------------------------------------------------------------------------
// Kernel 3: transpose x[b][ci][y][x] fp32 -> x_t2[b][y][cg(32)][x(64)][c8(8)] bf16
// grid = 512 (b*64+y), block = 256
// ---------------------------------------------------------------------------
__global__ void transpose_kernel(const float* __restrict__ x, bf16* __restrict__ xt) {
    const int bid = blockIdx.x;
    const int b = bid >> 6, y = bid & 63;
    const int t = threadIdx.x;
    __shared__ bf16 T[256 * 64];  // [ci][x]
    const float* src = x + (size_t)b * 256 * 4096 + (size_t)y * 64;
    for (int i = 0; i < 16; ++i) {
        int v = t + 256 * i;              // 4096 float4 chunks
        int ci = v >> 4, x4 = (v & 15) * 4;
        float4 f = *(const float4*)(src + (size_t)ci * 4096 + x4);
        bf16* d = &T[ci * 64 + x4];
        d[0] = (bf16)f.x; d[1] = (bf16)f.y; d[2] = (bf16)f.z; d[3] = (bf16)f.w;
    }
    __syncthreads();
    bf16* dstb = xt + (size_t)bid * 16384;
    for (int i = 0; i < 8; ++i) {
        int c2 = t + 256 * i;             // 2048 16B chunks: [cg][x]
        int cg = c2 >> 6, xx = c2 & 63;
        bf16x8 v;
#pragma unroll
        for (int c = 0; c < 8; ++c) v[c] = T[(cg * 8 + c) * 64 + xx];
        *(bf16x8*)(dstb + (size_t)c2 * 8) = v;
    }
}

// ---------------------------------------------------------------------------
// Kernel 4: implicit-GEMM conv + bias + residual.
// grid = 512: bid = [b(8)][half(2)][ytile(32)], block = 256 (4 waves, 2x2).
// Block tile: 128 co x (2 rows x 64 cols). K-loop: 4 ci-chunks of 64, 9 taps.
// ---------------------------------------------------------------------------
__global__ __launch_bounds__(256, 2) void conv_kernel(
    const bf16* __restrict__ xt, const bf16* __restrict__ aggw,
    const float* __restrict__ aggb, const float* __restrict__ xin,
    float* __restrict__ out) {
    const int bid = blockIdx.x;
    const int ytile = bid & 31;
    const int half = (bid >> 5) & 1;
    const int b = bid >> 6;
    const int tid = threadIdx.x;
    const int wave = tid >> 6, lane = tid & 63;
    const int wm = wave & 1, wn = wave >> 1;
    const int lane15 = lane & 15, quad = lane >> 4;

    __shared__ __align__(16) bf16 Xs[4][8][66][8];  // [row][cg][col(padded)][c8]
    __shared__ __align__(16) bf16 Ws[8][128][8];    // [cg][co_l][c8]

    f32x4 acc[4][4];
#pragma unroll
    for (int mt = 0; mt < 4; ++mt)
#pragma unroll
        for (int nt = 0; nt < 4; ++nt) acc[mt][nt] = f32x4{0.f, 0.f, 0.f, 0.f};

    // zero the whole X tile once: halo cols 0/65 and out-of-image rows stay 0.
    {
        uint4 z; z.x = z.y = z.z = z.w = 0u;
        uint4* p = (uint4*)&Xs[0][0][0][0];
        for (int i = tid; i < 2112; i += 256) p[i] = z;
    }

    const int yrow = ytile * 2 - 1 + wave;          // wave w stages halo row w
    const bool rowok = (yrow >= 0) && (yrow < 64);
    const bf16* xsrc = xt + ((size_t)b * 64 + (rowok ? yrow : 0)) * 16384 + (size_t)lane * 8;
    bf16* xdstbase = &Xs[wave][0][1][0];            // +cg*528 per cg

    for (int chunk = 0; chunk < 4; ++chunk) {
        __syncthreads();                            // prev compute done (and zero-fill)
        if (rowok) {
            const bf16* s0 = xsrc + (size_t)chunk * 4096;
#pragma unroll
            for (int cg = 0; cg < 8; ++cg)
                gload_lds16(s0 + cg * 512, xdstbase + cg * 528);
        }
        const bf16* wchunkbase = aggw + (((size_t)b * 36 + chunk) * 2 + half) * 8192;
        for (int pos = 0; pos < 9; ++pos) {
            if (pos) __syncthreads();               // prev tap done reading Ws
            const bf16* wsrc = wchunkbase + (size_t)pos * 65536 + wave * 2048 + (size_t)lane * 8;
            bf16* wdst = ((bf16*)Ws) + wave * 2048;
#pragma unroll
            for (int i = 0; i < 4; ++i)
                gload_lds16(wsrc + i * 512, wdst + i * 512);
            __syncthreads();                        // drains vmcnt (global_load_lds)
            const int kh = pos / 3, kw = pos - kh * 3;
            const int xr = wn + kh;
#pragma unroll
            for (int s = 0; s < 2; ++s) {
                const int cg = s * 4 + quad;
                bf16x8 afr[4], bfr[4];
#pragma unroll
                for (int mt = 0; mt < 4; ++mt)
                    afr[mt] = *(const bf16x8*)&Ws[cg][wm * 64 + mt * 16 + lane15][0];
#pragma unroll
                for (int nt = 0; nt < 4; ++nt)
                    bfr[nt] = *(const bf16x8*)&Xs[xr][cg][kw + nt * 16 + lane15][0];
#pragma unroll
                for (int mt = 0; mt < 4; ++mt)
#pragma unroll
                    for (int nt = 0; nt < 4; ++nt)
                        acc[mt][nt] = __builtin_amdgcn_mfma_f32_16x16x32_bf16(
                            afr[mt], bfr[nt], acc[mt][nt], 0, 0, 0);
            }
        }
    }

    // epilogue: conv + agg_b + residual, fp32 out
    const int y = ytile * 2 + wn;
#pragma unroll
    for (int mt = 0; mt < 4; ++mt) {
#pragma unroll
        for (int r = 0; r < 4; ++r) {
            const int co = half * 128 + wm * 64 + mt * 16 + quad * 4 + r;
            const float bbv = aggb[b * 256 + co];
            const size_t rowbase = (((size_t)b * 256 + co) * 64 + y) * 64;
#pragma unroll
            for (int nt = 0; nt < 4; ++nt) {
                const size_t oidx = rowbase + nt * 16 + lane15;
                out[oidx] = acc[mt][nt][r] + bbv + xin[oidx];
            }
        }
    }
}

// ---------------------------------------------------------------------------
extern "C" void kernel_launch(void* const* d_in, const int* in_sizes, int n_in,
                              void* d_out, int out_size, void* d_ws, size_t ws_size,
                              hipStream_t stream) {
    const float* x    = (const float*)d_in[0];  // [8,256,64,64]
    const float* sk   = (const float*)d_in[1];  // [8,1,56,56]
    const float* wgt  = (const float*)d_in[2];  // [16,256,256,3,3]
    const float* bias = (const float*)d_in[3];  // [16,256]
    const float* w1   = (const float*)d_in[4];  // [196,784]
    const float* w2   = (const float*)d_in[5];  // [16,196]
    float* out = (float*)d_out;

    char* ws = (char*)d_ws;
    float* att  = (float*)(ws + 0);                      // 512 B
    float* aggb = (float*)(ws + 1024);                   // 8 KB
    bf16*  aggw = (bf16*)(ws + 16384);                   // 9,437,184 B
    bf16*  xt   = (bf16*)(ws + 16384 + 9437184);         // 16,777,216 B

    attn_kernel<<<8, 256, 0, stream>>>(sk, w1, w2, att);
    agg_kernel<<<256, 256, 0, stream>>>(wgt, bias, att, aggw, aggb);
    transpose_kernel<<<512, 256, 0, stream>>>(x, xt);
    conv_kernel<<<512, 256, 0, stream>>>(xt, aggw, aggb, x, out);
}

// Round 2
// 189.944 us; speedup vs baseline: 1.3044x; 1.3044x over previous
//
#include <hip/hip_runtime.h>
#include <stdint.h>
#include <stddef.h>

typedef __bf16 bf16;
typedef __bf16 bf16x8 __attribute__((ext_vector_type(8)));
typedef __bf16 bf16x4 __attribute__((ext_vector_type(4)));
typedef float f32x4 __attribute__((ext_vector_type(4)));

static_assert(sizeof(bf16x8) == 16, "bf16x8 must be 16B");

__device__ __forceinline__ void gload_lds16(const void* g, void* l) {
    __builtin_amdgcn_global_load_lds(
        (const __attribute__((address_space(1))) uint32_t*)g,
        (__attribute__((address_space(3))) uint32_t*)l, 16, 0, 0);
}

// ---------------------------------------------------------------------------
// Kernel 1: attention  (pool 56x56 -> 28x28, MLP 784->196->16, softmax/T)
// grid = 8 (one block per sample), block = 256
// ---------------------------------------------------------------------------
__global__ void attn_kernel(const float* __restrict__ sk,
                            const float* __restrict__ w1,
                            const float* __restrict__ w2,
                            float* __restrict__ att) {
    const int b = blockIdx.x, t = threadIdx.x;
    __shared__ float pooled[784];
    __shared__ float hdn[196];
    __shared__ float logits[16];
    const float* skb = sk + (size_t)b * 3136;
    for (int e = t; e < 784; e += 256) {
        int oy = e / 28, ox = e % 28;
        const float* p = skb + (oy * 2) * 56 + ox * 2;
        pooled[e] = 0.25f * (p[0] + p[1] + p[56] + p[57]);
    }
    __syncthreads();
    if (t < 196) {
        float s = 0.f;
        const float* wr = w1 + (size_t)t * 784;
        for (int i = 0; i < 784; ++i) s += pooled[i] * wr[i];
        hdn[t] = s > 0.f ? s : 0.f;
    }
    __syncthreads();
    if (t < 16) {
        float s = 0.f;
        const float* wr = w2 + (size_t)t * 196;
        for (int j = 0; j < 196; ++j) s += hdn[j] * wr[j];
        logits[t] = s * (1.0f / 30.0f);
    }
    __syncthreads();
    if (t == 0) {
        float m = logits[0];
        for (int k = 1; k < 16; ++k) m = fmaxf(m, logits[k]);
        float e16[16], sum = 0.f;
        for (int k = 0; k < 16; ++k) { e16[k] = expf(logits[k] - m); sum += e16[k]; }
        float inv = 1.f / sum;
        for (int k = 0; k < 16; ++k) att[b * 16 + k] = e16[k] * inv;
    }
}

// ---------------------------------------------------------------------------
// Kernel 2: weight aggregation + bias aggregation.
// grid = 1024 (chunk-major: co = bid&255, chunk = bid>>8), block = 256.
// Threads t<144 each own one float4 of the (co,chunk) 576-float slab:
//   16 independent dwordx4 loads (one per expert k), register-accumulate all
//   8 samples, round to bf16, LDS transform, 16B stores in conv-DMA layout.
// agg_w2 layout: [b][pos][chunk(4)][half(2)][cg(8)][co_l(128)][c8(8)]  bf16
// ---------------------------------------------------------------------------
__global__ __launch_bounds__(256) void agg_kernel(
    const float* __restrict__ weight,
    const float* __restrict__ bias,
    const float* __restrict__ att,
    bf16* __restrict__ aggw,
    float* __restrict__ aggb) {
    const int bid = blockIdx.x;
    const int co = bid & 255, chunk = bid >> 8;
    const int t = threadIdx.x;

    __shared__ bf16 accW[8 * 576];  // [b][el]  (el = local e within chunk)

    if (chunk == 0 && t < 8) {
        float s = 0.f;
        for (int k = 0; k < 16; ++k) s += att[t * 16 + k] * bias[k * 256 + co];
        aggb[t * 256 + co] = s;
    }

    if (t < 144) {
        const float* wbase = weight + (size_t)co * 2304 + (size_t)chunk * 576 + (size_t)t * 4;
        float4 wv[16];
#pragma unroll
        for (int k = 0; k < 16; ++k)
            wv[k] = *(const float4*)(wbase + (size_t)k * 589824);
        float a[8][4];
#pragma unroll
        for (int b = 0; b < 8; ++b)
#pragma unroll
            for (int j = 0; j < 4; ++j) a[b][j] = 0.f;
#pragma unroll
        for (int k = 0; k < 16; ++k) {
#pragma unroll
            for (int b = 0; b < 8; ++b) {
                const float av = att[b * 16 + k];  // uniform -> scalar load
                a[b][0] += av * wv[k].x;
                a[b][1] += av * wv[k].y;
                a[b][2] += av * wv[k].z;
                a[b][3] += av * wv[k].w;
            }
        }
#pragma unroll
        for (int b = 0; b < 8; ++b) {
            bf16x4 v;
#pragma unroll
            for (int j = 0; j < 4; ++j) v[j] = (bf16)a[b][j];
            *(bf16x4*)&accW[b * 576 + t * 4] = v;
        }
    }
    __syncthreads();

    // write out in the conv-DMA-native layout
    const int half = co >> 7, co_l = co & 127;
    for (int s = t; s < 576; s += 256) {
        const int b = s / 72, r = s - b * 72;
        const int pos = r >> 3, cg = r & 7;
        bf16x8 v;
#pragma unroll
        for (int c = 0; c < 8; ++c) v[c] = accW[b * 576 + (cg * 8 + c) * 9 + pos];
        size_t o = (((((size_t)b * 9 + pos) * 4 + chunk) * 2 + half) * 8 + cg) * 128 + co_l;
        *(bf16x8*)(aggw + o * 8) = v;
    }
}

// ---------------------------------------------------------------------------
// Kernel 3: transpose x[b][ci][y][x] fp32 -> x_t2[b][y][cg(32)][x(64)][c8(8)] bf16
// grid = 512 (b*64+y), block = 256
// ---------------------------------------------------------------------------
__global__ void transpose_kernel(const float* __restrict__ x, bf16* __restrict__ xt) {
    const int bid = blockIdx.x;
    const int b = bid >> 6, y = bid & 63;
    const int t = threadIdx.x;
    __shared__ bf16 T[256 * 64];  // [ci][x]
    const float* src = x + (size_t)b * 256 * 4096 + (size_t)y * 64;
    for (int i = 0; i < 16; ++i) {
        int v = t + 256 * i;              // 4096 float4 chunks
        int ci = v >> 4, x4 = (v & 15) * 4;
        float4 f = *(const float4*)(src + (size_t)ci * 4096 + x4);
        bf16* d = &T[ci * 64 + x4];
        d[0] = (bf16)f.x; d[1] = (bf16)f.y; d[2] = (bf16)f.z; d[3] = (bf16)f.w;
    }
    __syncthreads();
    bf16* dstb = xt + (size_t)bid * 16384;
    for (int i = 0; i < 8; ++i) {
        int c2 = t + 256 * i;             // 2048 16B chunks: [cg][x]
        int cg = c2 >> 6, xx = c2 & 63;
        bf16x8 v;
#pragma unroll
        for (int c = 0; c < 8; ++c) v[c] = T[(cg * 8 + c) * 64 + xx];
        *(bf16x8*)(dstb + (size_t)c2 * 8) = v;
    }
}

// ---------------------------------------------------------------------------
// Kernel 4: implicit-GEMM conv + bias + residual.
// grid = 512: bid = [b(8)][half(2)][ytile(32)], block = 256 (4 waves, 2x2).
// Block tile: 128 co x (2 rows x 64 cols). K-loop: 4 ci-chunks of 64, 9 taps.
// ---------------------------------------------------------------------------
__global__ __launch_bounds__(256, 2) void conv_kernel(
    const bf16* __restrict__ xt, const bf16* __restrict__ aggw,
    const float* __restrict__ aggb, const float* __restrict__ xin,
    float* __restrict__ out) {
    const int bid = blockIdx.x;
    const int ytile = bid & 31;
    const int half = (bid >> 5) & 1;
    const int b = bid >> 6;
    const int tid = threadIdx.x;
    const int wave = tid >> 6, lane = tid & 63;
    const int wm = wave & 1, wn = wave >> 1;
    const int lane15 = lane & 15, quad = lane >> 4;

    __shared__ __align__(16) bf16 Xs[4][8][66][8];  // [row][cg][col(padded)][c8]
    __shared__ __align__(16) bf16 Ws[8][128][8];    // [cg][co_l][c8]

    f32x4 acc[4][4];
#pragma unroll
    for (int mt = 0; mt < 4; ++mt)
#pragma unroll
        for (int nt = 0; nt < 4; ++nt) acc[mt][nt] = f32x4{0.f, 0.f, 0.f, 0.f};

    // zero the whole X tile once: halo cols 0/65 and out-of-image rows stay 0.
    {
        uint4 z; z.x = z.y = z.z = z.w = 0u;
        uint4* p = (uint4*)&Xs[0][0][0][0];
        for (int i = tid; i < 2112; i += 256) p[i] = z;
    }

    const int yrow = ytile * 2 - 1 + wave;          // wave w stages halo row w
    const bool rowok = (yrow >= 0) && (yrow < 64);
    const bf16* xsrc = xt + ((size_t)b * 64 + (rowok ? yrow : 0)) * 16384 + (size_t)lane * 8;
    bf16* xdstbase = &Xs[wave][0][1][0];            // +cg*528 per cg

    for (int chunk = 0; chunk < 4; ++chunk) {
        __syncthreads();                            // prev compute done (and zero-fill)
        if (rowok) {
            const bf16* s0 = xsrc + (size_t)chunk * 4096;
#pragma unroll
            for (int cg = 0; cg < 8; ++cg)
                gload_lds16(s0 + cg * 512, xdstbase + cg * 528);
        }
        const bf16* wchunkbase = aggw + (((size_t)b * 36 + chunk) * 2 + half) * 8192;
        for (int pos = 0; pos < 9; ++pos) {
            if (pos) __syncthreads();               // prev tap done reading Ws
            const bf16* wsrc = wchunkbase + (size_t)pos * 65536 + wave * 2048 + (size_t)lane * 8;
            bf16* wdst = ((bf16*)Ws) + wave * 2048;
#pragma unroll
            for (int i = 0; i < 4; ++i)
                gload_lds16(wsrc + i * 512, wdst + i * 512);
            __syncthreads();                        // drains vmcnt (global_load_lds)
            const int kh = pos / 3, kw = pos - kh * 3;
            const int xr = wn + kh;
#pragma unroll
            for (int s = 0; s < 2; ++s) {
                const int cg = s * 4 + quad;
                bf16x8 afr[4], bfr[4];
#pragma unroll
                for (int mt = 0; mt < 4; ++mt)
                    afr[mt] = *(const bf16x8*)&Ws[cg][wm * 64 + mt * 16 + lane15][0];
#pragma unroll
                for (int nt = 0; nt < 4; ++nt)
                    bfr[nt] = *(const bf16x8*)&Xs[xr][cg][kw + nt * 16 + lane15][0];
#pragma unroll
                for (int mt = 0; mt < 4; ++mt)
#pragma unroll
                    for (int nt = 0; nt < 4; ++nt)
                        acc[mt][nt] = __builtin_amdgcn_mfma_f32_16x16x32_bf16(
                            afr[mt], bfr[nt], acc[mt][nt], 0, 0, 0);
            }
        }
    }

    // epilogue: conv + agg_b + residual, fp32 out
    const int y = ytile * 2 + wn;
#pragma unroll
    for (int mt = 0; mt < 4; ++mt) {
#pragma unroll
        for (int r = 0; r < 4; ++r) {
            const int co = half * 128 + wm * 64 + mt * 16 + quad * 4 + r;
            const float bbv = aggb[b * 256 + co];
            const size_t rowbase = (((size_t)b * 256 + co) * 64 + y) * 64;
#pragma unroll
            for (int nt = 0; nt < 4; ++nt) {
                const size_t oidx = rowbase + nt * 16 + lane15;
                out[oidx] = acc[mt][nt][r] + bbv + xin[oidx];
            }
        }
    }
}

// ---------------------------------------------------------------------------
extern "C" void kernel_launch(void* const* d_in, const int* in_sizes, int n_in,
                              void* d_out, int out_size, void* d_ws, size_t ws_size,
                              hipStream_t stream) {
    const float* x    = (const float*)d_in[0];  // [8,256,64,64]
    const float* sk   = (const float*)d_in[1];  // [8,1,56,56]
    const float* wgt  = (const float*)d_in[2];  // [16,256,256,3,3]
    const float* bias = (const float*)d_in[3];  // [16,256]
    const float* w1   = (const float*)d_in[4];  // [196,784]
    const float* w2   = (const float*)d_in[5];  // [16,196]
    float* out = (float*)d_out;

    char* ws = (char*)d_ws;
    float* att  = (float*)(ws + 0);                      // 512 B
    float* aggb = (float*)(ws + 1024);                   // 8 KB
    bf16*  aggw = (bf16*)(ws + 16384);                   // 9,437,184 B
    bf16*  xt   = (bf16*)(ws + 16384 + 9437184);         // 16,777,216 B

    attn_kernel<<<8, 256, 0, stream>>>(sk, w1, w2, att);
    agg_kernel<<<1024, 256, 0, stream>>>(wgt, bias, att, aggw, aggb);
    transpose_kernel<<<512, 256, 0, stream>>>(x, xt);
    conv_kernel<<<512, 256, 0, stream>>>(xt, aggw, aggb, x, out);
}